// Round 4
// baseline (1086.993 us; speedup 1.0000x reference)
//
#include <hip/hip_runtime.h>
#include <hip/hip_bf16.h>

#define B_ 64
#define S_ 4096
#define H_ 512
#define E_ 512
#define NEG_INF_ -1e10f

typedef __attribute__((ext_vector_type(8))) short short8;
typedef __attribute__((ext_vector_type(16))) float f32x16;

static __device__ __forceinline__ unsigned short f2bf(float f) {
    union { float f; unsigned u; } v; v.f = f;
    unsigned x = v.u;
    x += 0x7FFFu + ((x >> 16) & 1u);   // round-to-nearest-even
    return (unsigned short)(x >> 16);
}

// vendor RNE pair conversion (verified round 3: absmax 4.9e-4)
static __device__ __forceinline__ unsigned pk2(float lo, float hi) {
    float2 f; f.x = lo; f.y = hi;
    union { __hip_bfloat162 h; unsigned u; } c;
    c.h = __float22bfloat162_rn(f);
    return c.u;
}

static __device__ __forceinline__ void gload_lds16(const void* g, void* l) {
    __builtin_amdgcn_global_load_lds(
        (const __attribute__((address_space(1))) void*)g,
        (__attribute__((address_space(3))) void*)l, 16, 0, 0);
}

// ---------------- prep: Wkt[h][e] = bf16(Wk[e][h]) ----------------
__global__ void prep_wkt(const float* __restrict__ wk, unsigned short* __restrict__ wkt) {
    int idx = blockIdx.x * 256 + threadIdx.x;
    int h = idx >> 9, e = idx & 511;
    wkt[idx] = f2bf(wk[e * H_ + h]);
}

// ---------------- prep: qb[b][h] = hidden[b]@Wq[:,h] + bq[h] + bk[h] ----------------
__global__ void prep_qb(const float* __restrict__ hidden, const float* __restrict__ wq,
                        const float* __restrict__ bq, const float* __restrict__ bk,
                        float* __restrict__ qb) {
    __shared__ float hid[H_];
    int b = blockIdx.x, t = threadIdx.x;           // 256 threads
    hid[t]       = hidden[b * H_ + t];
    hid[t + 256] = hidden[b * H_ + t + 256];
    __syncthreads();
    for (int hh = t; hh < H_; hh += 256) {
        float s = 0.f;
        for (int e = 0; e < H_; ++e) s += hid[e] * wq[e * H_ + hh];
        qb[b * H_ + hh] = s + bq[hh] + bk[hh];
    }
}

// ---------------- main: partial scores over one 64-col n-chunk ----------------
// grid 16384: xcd-chunked -> (b, s-tile 128, n-tile 64). block 256 thr = 4 waves (2M x 2N),
// wave tile 64x32. A(enc) streamed to regs (half-kc granularity), B(Wkt) LDS dbuf per kc.
__global__ __launch_bounds__(256, 4) void scores_kernel(
    const float* __restrict__ enc, const unsigned short* __restrict__ wkt,
    const float* __restrict__ qb, const float* __restrict__ wv,
    float* __restrict__ part)
{
    __shared__ char lds[40960];                    // [0,16K): B dbuf; epilogue reuses all

    int id = blockIdx.x;
    int xcd = id & 7, q = id >> 3;
    int logical = xcd * 2048 + q;
    int b  = logical >> 8;
    int r  = logical & 255;
    int st = r >> 3, nt = r & 7;
    int s0 = st * 128;

    const int tid  = threadIdx.x;
    const int lane = tid & 63;
    const int wave = tid >> 6;
    const int wr   = wave >> 1;      // M half (0,1)
    const int wc   = wave & 1;       // N half (0,1)
    const int l31  = lane & 31;
    const int g    = lane >> 5;

    const float* encb  = enc + ((size_t)b * S_ + s0) * E_;
    const float* aBase = encb + (size_t)(wr * 64 + l31) * E_ + g * 8;

    // ---- B staging: tile = 64 rows x 64 K bf16 (8KB), source-permuted, linear LDS dest ----
    // stored[row][slot16] = logical[row][slot ^ (row&7)]
    auto stageB = [&](int kc, char* buf) {
#pragma unroll
        for (int j = 0; j < 2; ++j) {
            int brow = wave * 16 + j * 8;          // wave-uniform base row
            char* ldsb = buf + brow * 128;
            int row  = brow + (lane >> 3);
            int slot = (lane & 7) ^ (row & 7);
            const unsigned short* gp = wkt + (size_t)(nt * 64 + row) * H_ + kc * 64 + slot * 8;
            gload_lds16(gp, ldsb);
        }
    };

    float4 ar[2][2][2];
    short8 af[2][2];
    f32x16 acc[2];
#pragma unroll
    for (int mr = 0; mr < 2; ++mr)
#pragma unroll
        for (int e = 0; e < 16; ++e) acc[mr][e] = 0.f;

#define LOADA(hk_) do { \
    _Pragma("unroll") for (int mr = 0; mr < 2; ++mr) \
    _Pragma("unroll") for (int ks = 0; ks < 2; ++ks) { \
        const float* ap = aBase + (size_t)mr * (32 * E_) + (hk_) * 32 + ks * 16; \
        ar[mr][ks][0] = *(const float4*)ap; \
        ar[mr][ks][1] = *(const float4*)(ap + 4); } } while (0)

    // prologue
    stageB(0, lds);
    LOADA(0);

#pragma unroll
    for (int kc = 0; kc < 8; ++kc) {
        char* bt = lds + (kc & 1) * 8192;
        __syncthreads();                               // stage(kc) complete, prev buf free
        if (kc < 7) stageB(kc + 1, lds + ((kc + 1) & 1) * 8192);
#pragma unroll
        for (int h = 0; h < 2; ++h) {
            const int hk = kc * 2 + h;
            // convert A(hk) f32 -> bf16 frags (RNE)
#pragma unroll
            for (int mr = 0; mr < 2; ++mr)
#pragma unroll
                for (int ks = 0; ks < 2; ++ks) {
                    union { short8 s; unsigned u[4]; } u;
                    u.u[0] = pk2(ar[mr][ks][0].x, ar[mr][ks][0].y);
                    u.u[1] = pk2(ar[mr][ks][0].z, ar[mr][ks][0].w);
                    u.u[2] = pk2(ar[mr][ks][1].x, ar[mr][ks][1].y);
                    u.u[3] = pk2(ar[mr][ks][1].z, ar[mr][ks][1].w);
                    af[mr][ks] = u.s;
                }
            if (hk < 15) { LOADA(hk + 1); }
#pragma unroll
            for (int ks = 0; ks < 2; ++ks) {
                int brow = wc * 32 + l31;
                short8 bfr = *(const short8*)(bt + brow * 128 +
                              (((h * 2 + ks) * 32 + g * 16) ^ ((brow & 7) << 4)));
                acc[0] = __builtin_amdgcn_mfma_f32_32x32x16_bf16(af[0][ks], bfr, acc[0], 0, 0, 0);
                acc[1] = __builtin_amdgcn_mfma_f32_32x32x16_bf16(af[1][ks], bfr, acc[1], 0, 0, 0);
            }
        }
    }
#undef LOADA

    // ---- epilogue: p = Wv[col]*tanh(qb[col]+acc), col = nt*64 + wc*32 + l31 ----
    float p[2][16];
    {
        int col = nt * 64 + wc * 32 + l31;
        float qv  = qb[b * H_ + col];
        float wvv = wv[col];
#pragma unroll
        for (int mr = 0; mr < 2; ++mr)
#pragma unroll
            for (int e = 0; e < 16; ++e) {
                float x  = qv + acc[mr][e];
                float ex = __expf(2.f * x);
                float th = 1.f - 2.f / (ex + 1.f);
                p[mr][e] = wvv * th;
            }
    }

    __syncthreads();                                  // GEMM LDS reads done before reuse
    // ---- reduce over 32 lanes via LDS transpose (stride 36 floats, 16B aligned) ----
    float* ps = (float*)lds;                          // [wave][64 rows][36]
#pragma unroll
    for (int mr = 0; mr < 2; ++mr)
#pragma unroll
        for (int e = 0; e < 16; ++e) {
            int row = mr * 32 + (e & 3) + 8 * (e >> 2) + 4 * g;
            ps[(wave * 64 + row) * 36 + l31] = p[mr][e];
        }
    __syncthreads();
    float rsum = 0.f;
    {
        const float* myrow = ps + (size_t)(wave * 64 + lane) * 36;
#pragma unroll
        for (int j = 0; j < 8; ++j) {
            float4 v = *(const float4*)(myrow + j * 4);
            rsum += (v.x + v.y) + (v.z + v.w);
        }
    }
    float* pf = (float*)(lds + 36864);                // 256 floats
    pf[wave * 64 + lane] = rsum;
    __syncthreads();
    if (tid < 128) {
        int wr2 = tid >> 6, rr = tid & 63;
        float v = pf[(wr2 * 2 + 0) * 64 + rr] + pf[(wr2 * 2 + 1) * 64 + rr];
        int s = s0 + wr2 * 64 + rr;
        part[((size_t)b * S_ + s) * 8 + nt] = v;
    }
}

// ---------------- masked softmax over S per batch row (sums 8 partials) ----------------
__global__ void softmax_kernel(const float* __restrict__ part, const int* __restrict__ mask,
                               const float* __restrict__ bvp, float* __restrict__ attn) {
    __shared__ float red[8];
    int b = blockIdx.x, tid = threadIdx.x;         // 512 threads, 8 waves
    int wid = tid >> 6, lane = tid & 63;
    float bv0 = bvp[0];
    float vals[8];
    float mx = -3.4e38f;
#pragma unroll
    for (int i = 0; i < 8; ++i) {
        int s = i * 512 + tid;
        const float4* pp = (const float4*)(part + ((size_t)b * S_ + s) * 8);
        float4 v0 = pp[0], v1 = pp[1];
        float sc = ((v0.x + v0.y) + (v0.z + v0.w)) + ((v1.x + v1.y) + (v1.z + v1.w)) + bv0;
        sc = mask[(size_t)b * S_ + s] ? sc : NEG_INF_;
        vals[i] = sc;
        mx = fmaxf(mx, sc);
    }
#pragma unroll
    for (int off = 1; off < 64; off <<= 1) mx = fmaxf(mx, __shfl_xor(mx, off));
    if (lane == 0) red[wid] = mx;
    __syncthreads();
    mx = red[0];
#pragma unroll
    for (int w = 1; w < 8; ++w) mx = fmaxf(mx, red[w]);
    __syncthreads();
    float sum = 0.f;
#pragma unroll
    for (int i = 0; i < 8; ++i) { vals[i] = __expf(vals[i] - mx); sum += vals[i]; }
#pragma unroll
    for (int off = 1; off < 64; off <<= 1) sum += __shfl_xor(sum, off);
    if (lane == 0) red[wid] = sum;
    __syncthreads();
    sum = red[0] + red[1] + red[2] + red[3] + red[4] + red[5] + red[6] + red[7];
    float inv = 1.f / sum;
#pragma unroll
    for (int i = 0; i < 8; ++i) attn[(size_t)b * S_ + i * 512 + tid] = vals[i] * inv;
}

// ---------------- context partial sums: part[c][b][e] ----------------
__global__ void ctx_partial(const float* __restrict__ attn, const float* __restrict__ enc,
                            float* __restrict__ part) {
    __shared__ float a[256];
    int c = blockIdx.x, b = blockIdx.y, t = threadIdx.x;   // 256 threads
    a[t] = attn[(size_t)b * S_ + c * 256 + t];
    __syncthreads();
    const float* ep = enc + (size_t)b * S_ * E_ + (size_t)c * 256 * E_ + t * 2;
    float x = 0.f, y = 0.f;
#pragma unroll 4
    for (int s = 0; s < 256; ++s) {
        float2 v = *(const float2*)(ep + (size_t)s * E_);
        x += a[s] * v.x;
        y += a[s] * v.y;
    }
    float* o = part + ((size_t)c * B_ + b) * E_ + t * 2;
    o[0] = x; o[1] = y;
}

__global__ void ctx_reduce(const float* __restrict__ part, float* __restrict__ ctx) {
    int idx = blockIdx.x * 256 + threadIdx.x;       // 0..32767
    float s = 0.f;
#pragma unroll
    for (int c = 0; c < 16; ++c) s += part[(size_t)c * (B_ * E_) + idx];
    ctx[idx] = s;
}

extern "C" void kernel_launch(void* const* d_in, const int* in_sizes, int n_in,
                              void* d_out, int out_size, void* d_ws, size_t ws_size,
                              hipStream_t stream) {
    const float* hidden = (const float*)d_in[0];
    const float* enc    = (const float*)d_in[1];
    const int*   mask   = (const int*)d_in[2];
    const float* Wq     = (const float*)d_in[3];
    const float* bq     = (const float*)d_in[4];
    const float* Wk     = (const float*)d_in[5];
    const float* bk     = (const float*)d_in[6];
    const float* Wv     = (const float*)d_in[7];
    const float* bv     = (const float*)d_in[8];

    float* out  = (float*)d_out;               // [B*E context][B*S attn]
    char*  ws   = (char*)d_ws;
    float*          qbuf   = (float*)ws;                         // 131072 B
    unsigned short* wkt    = (unsigned short*)(ws + 131072);     // 524288 B
    float*          pscore = (float*)(ws + 655360);              // 8 MB [b][s][8]
    float*          cpart  = (float*)(ws + 655360);              // aliases pscore (after softmax)

    float* ctx  = out;
    float* attn = out + B_ * E_;

    prep_wkt<<<1024, 256, 0, stream>>>(Wk, wkt);
    prep_qb<<<64, 256, 0, stream>>>(hidden, Wq, bq, bk, qbuf);
    scores_kernel<<<16384, 256, 0, stream>>>(enc, wkt, qbuf, Wv, pscore);
    softmax_kernel<<<64, 512, 0, stream>>>(pscore, mask, bv, attn);
    ctx_partial<<<dim3(16, 64), 256, 0, stream>>>(attn, enc, cpart);
    ctx_reduce<<<128, 256, 0, stream>>>(cpart, ctx);
}

// Round 5
// 520.948 us; speedup vs baseline: 2.0866x; 2.0866x over previous
//
#include <hip/hip_runtime.h>
#include <hip/hip_bf16.h>

#define B_ 64
#define S_ 4096
#define H_ 512
#define E_ 512
#define NEG_INF_ -1e10f

typedef __attribute__((ext_vector_type(8))) short short8;
typedef __attribute__((ext_vector_type(16))) float f32x16;

static __device__ __forceinline__ unsigned short f2bf(float f) {
    union { float f; unsigned u; } v; v.f = f;
    unsigned x = v.u;
    x += 0x7FFFu + ((x >> 16) & 1u);   // round-to-nearest-even
    return (unsigned short)(x >> 16);
}

// vendor RNE pair conversion (verified r3: absmax 4.9e-4)
static __device__ __forceinline__ unsigned pk2(float lo, float hi) {
    float2 f; f.x = lo; f.y = hi;
    union { __hip_bfloat162 h; unsigned u; } c;
    c.h = __float22bfloat162_rn(f);
    return c.u;
}

static __device__ __forceinline__ void gload_lds16(const void* g, void* l) {
    __builtin_amdgcn_global_load_lds(
        (const __attribute__((address_space(1))) void*)g,
        (__attribute__((address_space(3))) void*)l, 16, 0, 0);
}

// ---------------- prep: Wkt[h][e] = bf16(Wk[e][h]) ----------------
__global__ void prep_wkt(const float* __restrict__ wk, unsigned short* __restrict__ wkt) {
    int idx = blockIdx.x * 256 + threadIdx.x;
    int h = idx >> 9, e = idx & 511;
    wkt[idx] = f2bf(wk[e * H_ + h]);
}

// ---------------- prep: qb[b][h] = hidden[b]@Wq[:,h] + bq[h] + bk[h] ----------------
__global__ void prep_qb(const float* __restrict__ hidden, const float* __restrict__ wq,
                        const float* __restrict__ bq, const float* __restrict__ bk,
                        float* __restrict__ qb) {
    __shared__ float hid[H_];
    int b = blockIdx.x, t = threadIdx.x;           // 256 threads
    hid[t]       = hidden[b * H_ + t];
    hid[t + 256] = hidden[b * H_ + t + 256];
    __syncthreads();
    for (int hh = t; hh < H_; hh += 256) {
        float s = 0.f;
        for (int e = 0; e < H_; ++e) s += hid[e] * wq[e * H_ + hh];
        qb[b * H_ + hh] = s + bq[hh] + bk[hh];
    }
}

// ---------------- main: partial scores over one 128-col n-chunk ----------------
// grid 8192: xcd-chunked -> (b, s-tile 128, n-tile 128). block 256 thr = 4 waves (2M x 2N).
// BOTH A (enc, f32) and B (Wkt, bf16) staged via global_load_lds DMA, double-buffered,
// kc = 32-k chunks, ONE barrier per kc (its vmcnt(0) drain retires the previous stage).
// LDS stored-row shape: 256B rows, 16B slots, slot ^ (storedrow & 15)  [r3: 0 conflicts]
__global__ __launch_bounds__(256, 4) void scores_kernel(
    const float* __restrict__ enc, const unsigned short* __restrict__ wkt,
    const float* __restrict__ qb, const float* __restrict__ wv,
    float* __restrict__ part)
{
    __shared__ char lds[49152];   // A0 @0 (16K), A1 @16K, B0 @32K (8K), B1 @40K

    int id = blockIdx.x;
    int xcd = id & 7, qq = id >> 3;
    int logical = xcd * 1024 + qq;
    int b  = logical >> 7;
    int r  = logical & 127;
    int st = r >> 2, nt = r & 3;
    int s0 = st * 128;

    const int tid  = threadIdx.x;
    const int lane = tid & 63;
    const int wave = tid >> 6;
    const int wr   = wave >> 1;      // M half (0,1)
    const int wc   = wave & 1;       // N half (0,1)
    const int l31  = lane & 31;
    const int g    = lane >> 5;

    const float* encb = enc + ((size_t)b * S_ + s0) * E_;

    // ---- A stage: 128 rows x 32 k f32 = 16KB. stored: [wrh 2][sr 32][ss 16]x16B,
    //      logical slot sl = ss ^ (sr&15); sl = mr*8 + q; row = wrh*64+mr*32+sr; k = q*4
    auto stageA = [&](int kc, char* buf) {
#pragma unroll
        for (int p = 0; p < 4; ++p) {
            int gi0 = p * 256 + wave * 64;
            char* db = buf + gi0 * 16;               // wave-uniform dest
            int gi  = gi0 + lane;
            int wrh = gi >> 9, gi9 = gi & 511;
            int sr  = gi9 >> 4, ss = gi9 & 15;
            int sl  = ss ^ (sr & 15);
            int row = wrh * 64 + (sl >> 3) * 32 + sr;
            const float* gp = encb + (size_t)row * 512 + kc * 32 + (sl & 7) * 4;
            gload_lds16(gp, db);
        }
    };
    // ---- B stage: 128 n x 32 k bf16 = 8KB. stored: [sn 32][ss 16]x16B,
    //      sl = ss ^ (sn&15); n = (sl>>2)*32 + sn; k = (sl&3)*8
    auto stageB = [&](int kc, char* buf) {
#pragma unroll
        for (int p = 0; p < 2; ++p) {
            int gi0 = p * 256 + wave * 64;
            char* db = buf + gi0 * 16;
            int gi = gi0 + lane;
            int sn = gi >> 4, ss = gi & 15;
            int sl = ss ^ (sn & 15);
            int n  = (sl >> 2) * 32 + sn;
            const unsigned short* gp = wkt + (size_t)(nt * 128 + n) * 512 + kc * 32 + (sl & 3) * 8;
            gload_lds16(gp, db);
        }
    };

    f32x16 acc[2][2];
#pragma unroll
    for (int mr = 0; mr < 2; ++mr)
#pragma unroll
        for (int nf = 0; nf < 2; ++nf)
#pragma unroll
            for (int e = 0; e < 16; ++e) acc[mr][nf][e] = 0.f;

    // prologue
    stageA(0, lds);
    stageB(0, lds + 32768);

    for (int kc = 0; kc < 16; ++kc) {
        __syncthreads();                 // drains stage(kc) DMAs; frees buf (kc-1)&1
        if (kc < 15) {
            stageA(kc + 1, lds + ((kc + 1) & 1) * 16384);
            stageB(kc + 1, lds + 32768 + ((kc + 1) & 1) * 8192);
        }
        const char* Ab = lds + (kc & 1) * 16384 + wr * 8192;
        const char* Bb = lds + 32768 + (kc & 1) * 8192;
#pragma unroll
        for (int ks = 0; ks < 2; ++ks) {
            short8 af[2];
#pragma unroll
            for (int mr = 0; mr < 2; ++mr) {
                int sl0 = mr * 8 + ks * 4 + g * 2;
                float4 r0 = *(const float4*)(Ab + l31 * 256 + ((sl0 ^ (l31 & 15)) << 4));
                float4 r1 = *(const float4*)(Ab + l31 * 256 + (((sl0 + 1) ^ (l31 & 15)) << 4));
                union { short8 s; unsigned u[4]; } u;
                u.u[0] = pk2(r0.x, r0.y); u.u[1] = pk2(r0.z, r0.w);
                u.u[2] = pk2(r1.x, r1.y); u.u[3] = pk2(r1.z, r1.w);
                af[mr] = u.s;
            }
#pragma unroll
            for (int nf = 0; nf < 2; ++nf) {
                int sl = (wc * 2 + nf) * 4 + ks * 2 + g;
                short8 bfr = *(const short8*)(Bb + l31 * 256 + ((sl ^ (l31 & 15)) << 4));
                acc[0][nf] = __builtin_amdgcn_mfma_f32_32x32x16_bf16(af[0], bfr, acc[0][nf], 0, 0, 0);
                acc[1][nf] = __builtin_amdgcn_mfma_f32_32x32x16_bf16(af[1], bfr, acc[1][nf], 0, 0, 0);
            }
        }
    }

    // ---- epilogue: p = sum_nf Wv[col]*tanh(qb[col]+acc) ----
    float p[2][16];
#pragma unroll
    for (int nf = 0; nf < 2; ++nf) {
        int col = nt * 128 + wc * 64 + nf * 32 + l31;
        float qv  = qb[b * H_ + col];
        float wvv = wv[col];
#pragma unroll
        for (int mr = 0; mr < 2; ++mr)
#pragma unroll
            for (int e = 0; e < 16; ++e) {
                float x  = qv + acc[mr][nf][e];
                float ex = __expf(2.f * x);
                float th = 1.f - 2.f / (ex + 1.f);
                float v  = wvv * th;
                p[mr][e] = nf ? (p[mr][e] + v) : v;
            }
    }

    __syncthreads();                                  // GEMM LDS reads done before reuse
    // ---- reduce over 32 lanes via LDS transpose (stride 36 floats; r3-verified) ----
    float* ps = (float*)lds;                          // [wave][64 rows][36]
#pragma unroll
    for (int mr = 0; mr < 2; ++mr)
#pragma unroll
        for (int e = 0; e < 16; ++e) {
            int row = mr * 32 + (e & 3) + 8 * (e >> 2) + 4 * g;
            ps[(wave * 64 + row) * 36 + l31] = p[mr][e];
        }
    __syncthreads();
    float rsum = 0.f;
    {
        const float* myrow = ps + (size_t)(wave * 64 + lane) * 36;
#pragma unroll
        for (int j = 0; j < 8; ++j) {
            float4 v = *(const float4*)(myrow + j * 4);
            rsum += (v.x + v.y) + (v.z + v.w);
        }
    }
    float* pf = (float*)(lds + 36864);                // 256 floats
    pf[wave * 64 + lane] = rsum;
    __syncthreads();
    if (tid < 128) {
        int wr2 = tid >> 6, rr = tid & 63;
        float v = pf[(wr2 * 2 + 0) * 64 + rr] + pf[(wr2 * 2 + 1) * 64 + rr];
        int s = s0 + wr2 * 64 + rr;
        part[((size_t)b * S_ + s) * 4 + nt] = v;
    }
}

// ---------------- masked softmax over S per batch row (sums 4 partials) ----------------
__global__ void softmax_kernel(const float* __restrict__ part, const int* __restrict__ mask,
                               const float* __restrict__ bvp, float* __restrict__ attn) {
    __shared__ float red[8];
    int b = blockIdx.x, tid = threadIdx.x;         // 512 threads, 8 waves
    int wid = tid >> 6, lane = tid & 63;
    float bv0 = bvp[0];
    float vals[8];
    float mx = -3.4e38f;
#pragma unroll
    for (int i = 0; i < 8; ++i) {
        int s = i * 512 + tid;
        float4 v = *(const float4*)(part + ((size_t)b * S_ + s) * 4);
        float sc = (v.x + v.y) + (v.z + v.w) + bv0;
        sc = mask[(size_t)b * S_ + s] ? sc : NEG_INF_;
        vals[i] = sc;
        mx = fmaxf(mx, sc);
    }
#pragma unroll
    for (int off = 1; off < 64; off <<= 1) mx = fmaxf(mx, __shfl_xor(mx, off));
    if (lane == 0) red[wid] = mx;
    __syncthreads();
    mx = red[0];
#pragma unroll
    for (int w = 1; w < 8; ++w) mx = fmaxf(mx, red[w]);
    __syncthreads();
    float sum = 0.f;
#pragma unroll
    for (int i = 0; i < 8; ++i) { vals[i] = __expf(vals[i] - mx); sum += vals[i]; }
#pragma unroll
    for (int off = 1; off < 64; off <<= 1) sum += __shfl_xor(sum, off);
    if (lane == 0) red[wid] = sum;
    __syncthreads();
    sum = red[0] + red[1] + red[2] + red[3] + red[4] + red[5] + red[6] + red[7];
    float inv = 1.f / sum;
#pragma unroll
    for (int i = 0; i < 8; ++i) attn[(size_t)b * S_ + i * 512 + tid] = vals[i] * inv;
}

// ---------------- context partial sums: part[c][b][e] ----------------
__global__ void ctx_partial(const float* __restrict__ attn, const float* __restrict__ enc,
                            float* __restrict__ part) {
    __shared__ float a[256];
    int c = blockIdx.x, b = blockIdx.y, t = threadIdx.x;   // 256 threads
    a[t] = attn[(size_t)b * S_ + c * 256 + t];
    __syncthreads();
    const float* ep = enc + (size_t)b * S_ * E_ + (size_t)c * 256 * E_ + t * 2;
    float x = 0.f, y = 0.f;
#pragma unroll 4
    for (int s = 0; s < 256; ++s) {
        float2 v = *(const float2*)(ep + (size_t)s * E_);
        x += a[s] * v.x;
        y += a[s] * v.y;
    }
    float* o = part + ((size_t)c * B_ + b) * E_ + t * 2;
    o[0] = x; o[1] = y;
}

__global__ void ctx_reduce(const float* __restrict__ part, float* __restrict__ ctx) {
    int idx = blockIdx.x * 256 + threadIdx.x;       // 0..32767
    float s = 0.f;
#pragma unroll
    for (int c = 0; c < 16; ++c) s += part[(size_t)c * (B_ * E_) + idx];
    ctx[idx] = s;
}

extern "C" void kernel_launch(void* const* d_in, const int* in_sizes, int n_in,
                              void* d_out, int out_size, void* d_ws, size_t ws_size,
                              hipStream_t stream) {
    const float* hidden = (const float*)d_in[0];
    const float* enc    = (const float*)d_in[1];
    const int*   mask   = (const int*)d_in[2];
    const float* Wq     = (const float*)d_in[3];
    const float* bq     = (const float*)d_in[4];
    const float* Wk     = (const float*)d_in[5];
    const float* bk     = (const float*)d_in[6];
    const float* Wv     = (const float*)d_in[7];
    const float* bv     = (const float*)d_in[8];

    float* out  = (float*)d_out;               // [B*E context][B*S attn]
    char*  ws   = (char*)d_ws;
    float*          qbuf   = (float*)ws;                         // 131072 B
    unsigned short* wkt    = (unsigned short*)(ws + 131072);     // 524288 B
    float*          pscore = (float*)(ws + 655360);              // 4 MB [b][s][4]
    float*          cpart  = (float*)(ws + 655360);              // aliases pscore (after softmax)

    float* ctx  = out;
    float* attn = out + B_ * E_;

    prep_wkt<<<1024, 256, 0, stream>>>(Wk, wkt);
    prep_qb<<<64, 256, 0, stream>>>(hidden, Wq, bq, bk, qbuf);
    scores_kernel<<<8192, 256, 0, stream>>>(enc, wkt, qbuf, Wv, pscore);
    softmax_kernel<<<64, 512, 0, stream>>>(pscore, mask, bv, attn);
    ctx_partial<<<dim3(16, 64), 256, 0, stream>>>(attn, enc, cpart);
    ctx_reduce<<<128, 256, 0, stream>>>(cpart, ctx);
}

// Round 6
// 441.893 us; speedup vs baseline: 2.4599x; 1.1789x over previous
//
#include <hip/hip_runtime.h>
#include <hip/hip_bf16.h>

#define B_ 64
#define S_ 4096
#define H_ 512
#define E_ 512
#define NEG_INF_ -1e10f

typedef __attribute__((ext_vector_type(8))) short short8;
typedef __attribute__((ext_vector_type(16))) float f32x16;

static __device__ __forceinline__ unsigned short f2bf(float f) {
    union { float f; unsigned u; } v; v.f = f;
    unsigned x = v.u;
    x += 0x7FFFu + ((x >> 16) & 1u);   // round-to-nearest-even
    return (unsigned short)(x >> 16);
}

// vendor RNE pair conversion (verified r3/r5: absmax 4.9e-4)
static __device__ __forceinline__ unsigned pk2(float lo, float hi) {
    float2 f; f.x = lo; f.y = hi;
    union { __hip_bfloat162 h; unsigned u; } c;
    c.h = __float22bfloat162_rn(f);
    return c.u;
}

static __device__ __forceinline__ void gload_lds16(const void* g, void* l) {
    __builtin_amdgcn_global_load_lds(
        (const __attribute__((address_space(1))) void*)g,
        (__attribute__((address_space(3))) void*)l, 16, 0, 0);
}

#define VMCNT6 do { asm volatile("s_waitcnt vmcnt(6)" ::: "memory"); __builtin_amdgcn_sched_barrier(0); } while (0)
#define VMCNT0 do { asm volatile("s_waitcnt vmcnt(0)" ::: "memory"); __builtin_amdgcn_sched_barrier(0); } while (0)
#define LGKM0  do { asm volatile("s_waitcnt lgkmcnt(0)" ::: "memory"); __builtin_amdgcn_sched_barrier(0); } while (0)

// ---------------- prep: Wkt[h][e] = bf16(Wk[e][h]) ----------------
__global__ void prep_wkt(const float* __restrict__ wk, unsigned short* __restrict__ wkt) {
    int idx = blockIdx.x * 256 + threadIdx.x;
    int h = idx >> 9, e = idx & 511;
    wkt[idx] = f2bf(wk[e * H_ + h]);
}

// ---------------- prep: qb[b][h] = hidden[b]@Wq[:,h] + bq[h] + bk[h] ----------------
__global__ void prep_qb(const float* __restrict__ hidden, const float* __restrict__ wq,
                        const float* __restrict__ bq, const float* __restrict__ bk,
                        float* __restrict__ qb) {
    __shared__ float hid[H_];
    int b = blockIdx.x, t = threadIdx.x;           // 256 threads
    hid[t]       = hidden[b * H_ + t];
    hid[t + 256] = hidden[b * H_ + t + 256];
    __syncthreads();
    for (int hh = t; hh < H_; hh += 256) {
        float s = 0.f;
        for (int e = 0; e < H_; ++e) s += hid[e] * wq[e * H_ + hh];
        qb[b * H_ + hh] = s + bq[hh] + bk[hh];
    }
}

// ---------------- main: partial scores over one 128-col n-chunk ----------------
// grid 8192: xcd-chunked -> (b, s-tile 128, n-tile 128). block 256 thr = 4 waves (2M x 2N).
// A (enc f32) -> regs -> cvt bf16 -> ds_write (2-buf ping-pong).
// B (Wkt bf16) -> global_load_lds DMA (3-buf ring).
// Counted-vmcnt pipeline, raw s_barrier (one per kc), 2-stage prefetch depth.
// LDS stored-row shape everywhere: 256B rows, 16 slots x 16B, slot ^ (srow&15) [0-conflict, r3/r5]
__global__ __launch_bounds__(256, 3) void scores_kernel(
    const float* __restrict__ enc, const unsigned short* __restrict__ wkt,
    const float* __restrict__ qb, const float* __restrict__ wv,
    float* __restrict__ part)
{
    __shared__ char lds[40960];   // A0@0, A1@8K, B0@16K, B1@24K, B2@32K

    int id = blockIdx.x;
    int xcd = id & 7, qq = id >> 3;
    int logical = xcd * 1024 + qq;
    int b  = logical >> 7;
    int r  = logical & 127;
    int st = r >> 2, nt = r & 3;
    int s0 = st * 128;

    const int tid  = threadIdx.x;
    const int lane = tid & 63;
    const int wave = tid >> 6;
    const int wr   = wave >> 1;      // M half (0,1)
    const int wc   = wave & 1;       // N half (0,1)
    const int l31  = lane & 31;
    const int g    = lane >> 5;

    const float* encb = enc + ((size_t)b * S_ + s0) * E_;

    // ---- A: thread t handles slotids 2t,2t+1; slotid -> row=sid>>2 (0..127), ksl=sid&3 (k=ksl*8) ----
    auto loadA = [&](int kc, float4 (&rg)[4]) {
#pragma unroll
        for (int j = 0; j < 2; ++j) {
            int sid = tid * 2 + j;
            int row = sid >> 2, ksl = sid & 3;
            const float* p = encb + (size_t)row * 512 + kc * 32 + ksl * 8;
            rg[j * 2 + 0] = *(const float4*)p;
            rg[j * 2 + 1] = *(const float4*)(p + 4);
        }
    };
    auto writeA = [&](char* buf, const float4 (&rg)[4]) {
#pragma unroll
        for (int j = 0; j < 2; ++j) {
            int sid = tid * 2 + j;
            int row = sid >> 2, ksl = sid & 3;
            int srow = row & 31;
            int sst  = ((row >> 5) * 4 + ksl) ^ (srow & 15);
            union { short8 s; unsigned u[4]; } u;
            u.u[0] = pk2(rg[j * 2].x, rg[j * 2].y);
            u.u[1] = pk2(rg[j * 2].z, rg[j * 2].w);
            u.u[2] = pk2(rg[j * 2 + 1].x, rg[j * 2 + 1].y);
            u.u[3] = pk2(rg[j * 2 + 1].z, rg[j * 2 + 1].w);
            *(short8*)(buf + srow * 256 + sst * 16) = u.s;
        }
    };
    // ---- B: 128 n x 32 k bf16 = 8KB DMA; stored [sn 32][16]: sl = ss^(sn&15); n=(sl>>2)*32+sn; k=(sl&3)*8
    auto stageB = [&](int kc, char* buf) {
#pragma unroll
        for (int p = 0; p < 2; ++p) {
            int gi0 = p * 256 + wave * 64;
            char* db = buf + gi0 * 16;                 // wave-uniform dest
            int gi = gi0 + lane;
            int sn = gi >> 4, ss = gi & 15;
            int sl = ss ^ (sn & 15);
            int n  = (sl >> 2) * 32 + sn;
            const unsigned short* gp = wkt + (size_t)(nt * 128 + n) * 512 + kc * 32 + (sl & 3) * 8;
            gload_lds16(gp, db);
        }
    };

    f32x16 acc[2][2];
#pragma unroll
    for (int mr = 0; mr < 2; ++mr)
#pragma unroll
        for (int nf = 0; nf < 2; ++nf)
#pragma unroll
            for (int e = 0; e < 16; ++e) acc[mr][nf][e] = 0.f;

    float4 ra[4], rb[4];

    // prologue: 2 stages in flight (6 vm-ops each: 4 A dwordx4 + 2 B DMA)
    loadA(0, ra); stageB(0, lds + 16384);
    loadA(1, rb); stageB(1, lds + 16384 + 8192);

    auto iter = [&](int kc, float4 (&rg)[4]) {
        if (kc < 15) { VMCNT6; } else { VMCNT0; }       // stage kc retired
        char* Ab = lds + (kc & 1) * 8192;
        writeA(Ab, rg);                                  // publish A(kc)
        LGKM0;
        __builtin_amdgcn_s_barrier();
        __builtin_amdgcn_sched_barrier(0);
        if (kc < 14) {                                   // issue stage kc+2
            loadA(kc + 2, rg);
            stageB(kc + 2, lds + 16384 + ((kc + 2) % 3) * 8192);
        }
        const char* Bb = lds + 16384 + (kc % 3) * 8192;
#pragma unroll
        for (int ks = 0; ks < 2; ++ks) {
            short8 af[2], bf[2];
#pragma unroll
            for (int mr = 0; mr < 2; ++mr) {
                int slog = (wr * 2 + mr) * 4 + ks * 2 + g;
                af[mr] = *(const short8*)(Ab + l31 * 256 + ((slog ^ (l31 & 15)) << 4));
            }
#pragma unroll
            for (int nf = 0; nf < 2; ++nf) {
                int sl = (wc * 2 + nf) * 4 + ks * 2 + g;
                bf[nf] = *(const short8*)(Bb + l31 * 256 + ((sl ^ (l31 & 15)) << 4));
            }
            acc[0][0] = __builtin_amdgcn_mfma_f32_32x32x16_bf16(af[0], bf[0], acc[0][0], 0, 0, 0);
            acc[0][1] = __builtin_amdgcn_mfma_f32_32x32x16_bf16(af[0], bf[1], acc[0][1], 0, 0, 0);
            acc[1][0] = __builtin_amdgcn_mfma_f32_32x32x16_bf16(af[1], bf[0], acc[1][0], 0, 0, 0);
            acc[1][1] = __builtin_amdgcn_mfma_f32_32x32x16_bf16(af[1], bf[1], acc[1][1], 0, 0, 0);
        }
    };

    for (int t2 = 0; t2 < 8; ++t2) {
        iter(t2 * 2,     ra);
        iter(t2 * 2 + 1, rb);
    }

    // ---- epilogue: p = sum_nf Wv[col]*tanh(qb[col]+acc) ----
    float p[2][16];
#pragma unroll
    for (int nf = 0; nf < 2; ++nf) {
        int col = nt * 128 + wc * 64 + nf * 32 + l31;
        float qv  = qb[b * H_ + col];
        float wvv = wv[col];
#pragma unroll
        for (int mr = 0; mr < 2; ++mr)
#pragma unroll
            for (int e = 0; e < 16; ++e) {
                float x  = qv + acc[mr][nf][e];
                float ex = __expf(2.f * x);
                float th = 1.f - 2.f / (ex + 1.f);
                float v  = wvv * th;
                p[mr][e] = nf ? (p[mr][e] + v) : v;
            }
    }

    __syncthreads();                                  // all GEMM LDS traffic done before reuse
    // ---- reduce over 32 lanes via LDS transpose (stride 36 floats; r3-verified) ----
    float* ps = (float*)lds;                          // [wave][64 rows][36]
#pragma unroll
    for (int mr = 0; mr < 2; ++mr)
#pragma unroll
        for (int e = 0; e < 16; ++e) {
            int row = mr * 32 + (e & 3) + 8 * (e >> 2) + 4 * g;
            ps[(wave * 64 + row) * 36 + l31] = p[mr][e];
        }
    __syncthreads();
    float rsum = 0.f;
    {
        const float* myrow = ps + (size_t)(wave * 64 + lane) * 36;
#pragma unroll
        for (int j = 0; j < 8; ++j) {
            float4 v = *(const float4*)(myrow + j * 4);
            rsum += (v.x + v.y) + (v.z + v.w);
        }
    }
    float* pf = (float*)(lds + 36864);                // 256 floats
    pf[wave * 64 + lane] = rsum;
    __syncthreads();
    if (tid < 128) {
        int wr2 = tid >> 6, rr = tid & 63;
        float v = pf[(wr2 * 2 + 0) * 64 + rr] + pf[(wr2 * 2 + 1) * 64 + rr];
        int s = s0 + wr2 * 64 + rr;
        part[((size_t)b * S_ + s) * 4 + nt] = v;
    }
}

// ---------------- masked softmax over S per batch row (sums 4 partials) ----------------
__global__ void softmax_kernel(const float* __restrict__ part, const int* __restrict__ mask,
                               const float* __restrict__ bvp, float* __restrict__ attn) {
    __shared__ float red[8];
    int b = blockIdx.x, tid = threadIdx.x;         // 512 threads, 8 waves
    int wid = tid >> 6, lane = tid & 63;
    float bv0 = bvp[0];
    float vals[8];
    float mx = -3.4e38f;
#pragma unroll
    for (int i = 0; i < 8; ++i) {
        int s = i * 512 + tid;
        float4 v = *(const float4*)(part + ((size_t)b * S_ + s) * 4);
        float sc = (v.x + v.y) + (v.z + v.w) + bv0;
        sc = mask[(size_t)b * S_ + s] ? sc : NEG_INF_;
        vals[i] = sc;
        mx = fmaxf(mx, sc);
    }
#pragma unroll
    for (int off = 1; off < 64; off <<= 1) mx = fmaxf(mx, __shfl_xor(mx, off));
    if (lane == 0) red[wid] = mx;
    __syncthreads();
    mx = red[0];
#pragma unroll
    for (int w = 1; w < 8; ++w) mx = fmaxf(mx, red[w]);
    __syncthreads();
    float sum = 0.f;
#pragma unroll
    for (int i = 0; i < 8; ++i) { vals[i] = __expf(vals[i] - mx); sum += vals[i]; }
#pragma unroll
    for (int off = 1; off < 64; off <<= 1) sum += __shfl_xor(sum, off);
    if (lane == 0) red[wid] = sum;
    __syncthreads();
    sum = red[0] + red[1] + red[2] + red[3] + red[4] + red[5] + red[6] + red[7];
    float inv = 1.f / sum;
#pragma unroll
    for (int i = 0; i < 8; ++i) attn[(size_t)b * S_ + i * 512 + tid] = vals[i] * inv;
}

// ---------------- context partial sums: part[c][b][e] ----------------
__global__ void ctx_partial(const float* __restrict__ attn, const float* __restrict__ enc,
                            float* __restrict__ part) {
    __shared__ float a[256];
    int c = blockIdx.x, b = blockIdx.y, t = threadIdx.x;   // 256 threads
    a[t] = attn[(size_t)b * S_ + c * 256 + t];
    __syncthreads();
    const float* ep = enc + (size_t)b * S_ * E_ + (size_t)c * 256 * E_ + t * 2;
    float x = 0.f, y = 0.f;
#pragma unroll 4
    for (int s = 0; s < 256; ++s) {
        float2 v = *(const float2*)(ep + (size_t)s * E_);
        x += a[s] * v.x;
        y += a[s] * v.y;
    }
    float* o = part + ((size_t)c * B_ + b) * E_ + t * 2;
    o[0] = x; o[1] = y;
}

__global__ void ctx_reduce(const float* __restrict__ part, float* __restrict__ ctx) {
    int idx = blockIdx.x * 256 + threadIdx.x;       // 0..32767
    float s = 0.f;
#pragma unroll
    for (int c = 0; c < 16; ++c) s += part[(size_t)c * (B_ * E_) + idx];
    ctx[idx] = s;
}

extern "C" void kernel_launch(void* const* d_in, const int* in_sizes, int n_in,
                              void* d_out, int out_size, void* d_ws, size_t ws_size,
                              hipStream_t stream) {
    const float* hidden = (const float*)d_in[0];
    const float* enc    = (const float*)d_in[1];
    const int*   mask   = (const int*)d_in[2];
    const float* Wq     = (const float*)d_in[3];
    const float* bq     = (const float*)d_in[4];
    const float* Wk     = (const float*)d_in[5];
    const float* bk     = (const float*)d_in[6];
    const float* Wv     = (const float*)d_in[7];
    const float* bv     = (const float*)d_in[8];

    float* out  = (float*)d_out;               // [B*E context][B*S attn]
    char*  ws   = (char*)d_ws;
    float*          qbuf   = (float*)ws;                         // 131072 B
    unsigned short* wkt    = (unsigned short*)(ws + 131072);     // 524288 B
    float*          pscore = (float*)(ws + 655360);              // 4 MB [b][s][4]
    float*          cpart  = (float*)(ws + 655360);              // aliases pscore (after softmax)

    float* ctx  = out;
    float* attn = out + B_ * E_;

    prep_wkt<<<1024, 256, 0, stream>>>(Wk, wkt);
    prep_qb<<<64, 256, 0, stream>>>(hidden, Wq, bq, bk, qbuf);
    scores_kernel<<<8192, 256, 0, stream>>>(enc, wkt, qbuf, Wv, pscore);
    softmax_kernel<<<64, 512, 0, stream>>>(pscore, mask, bv, attn);
    ctx_partial<<<dim3(16, 64), 256, 0, stream>>>(attn, enc, cpart);
    ctx_reduce<<<128, 256, 0, stream>>>(cpart, ctx);
}